// Round 4
// baseline (271.212 us; speedup 1.0000x reference)
//
#include <hip/hip_runtime.h>
#include <hip/hip_bf16.h>

typedef __attribute__((ext_vector_type(8))) short short8;
typedef __attribute__((ext_vector_type(4))) float f32x4;

#define NCELL 8192
#define NGENE 10000
#define KD 32
#define ZD 100
#define HD 256
#define GD 100   // z_dim of output (gen_Z rows)
#define NGB 625  // gene blocks

__device__ __forceinline__ float gelu_exact(float x) {
    return 0.5f * x * (1.0f + erff(x * 0.70710678118654752f));
}
__device__ __forceinline__ ushort bf16bits(float x) {
    __hip_bfloat16 h = __float2bfloat16(x);
    return *reinterpret_cast<ushort*>(&h);
}

// ---------------- Kernel 1: keys -> bf16 hi/lo B-fragments (col=cell&15, k=8*(l'>>4)+j),
// plus Kmax2 = max_c ||k_c||^2
__global__ void key_kernel(const float* __restrict__ rawZ,
                           const float* __restrict__ Wz1, const float* __restrict__ bz1,
                           const float* __restrict__ Wz2, const float* __restrict__ bz2,
                           ushort* __restrict__ khiB, ushort* __restrict__ kloB,
                           unsigned* __restrict__ kmax2u) {
    __shared__ float z[8][ZD];
    __shared__ float h[8][HD];
    const int t = threadIdx.x;
    const int c0 = blockIdx.x * 8;
    for (int idx = t; idx < 8 * ZD; idx += 256) {
        int cell = idx / ZD, i = idx - cell * ZD;
        z[cell][i] = rawZ[i * NCELL + c0 + cell];
    }
    __syncthreads();
    float a[8];
#pragma unroll
    for (int cl = 0; cl < 8; ++cl) a[cl] = bz1[t];
    for (int i = 0; i < ZD; ++i) {
        float wv = Wz1[i * HD + t];
#pragma unroll
        for (int cl = 0; cl < 8; ++cl) a[cl] += z[cl][i] * wv;
    }
#pragma unroll
    for (int cl = 0; cl < 8; ++cl) h[cl][t] = gelu_exact(a[cl]);
    __syncthreads();
    const int cell = t >> 5, kk = t & 31;
    float b = bz2[kk];
    for (int j = 0; j < HD; ++j) b += h[cell][j] * Wz2[j * KD + kk];
    const int c = c0 + cell;
    __hip_bfloat16 hi = __float2bfloat16(b);
    float hif = __bfloat162float(hi);
    int idx = ((c >> 4) * 64 + (c & 15) + 16 * (kk >> 3)) * 8 + (kk & 7);
    khiB[idx] = *reinterpret_cast<ushort*>(&hi);
    kloB[idx] = bf16bits(b - hif);
    float sq = b * b;
#pragma unroll
    for (int off = 16; off > 0; off >>= 1) sq += __shfl_xor(sq, off, 32);
    if (kk == 0) atomicMax(kmax2u, __float_as_uint(sq));
}

// ---------------- Kernel 2: q -> bf16 hi/lo A-fragments (row=g&15, k=8*(l'>>4)+j), Mg bound
__global__ void query_kernel(const float* __restrict__ Grep,
                             const float* __restrict__ Wg1, const float* __restrict__ bg1,
                             const float* __restrict__ Wg2, const float* __restrict__ bg2,
                             const unsigned* __restrict__ kmax2u,
                             ushort* __restrict__ qAhi, ushort* __restrict__ qAlo,
                             float* __restrict__ Mg) {
    __shared__ float gr[8][GD];
    __shared__ float hq[8][KD];
    const int t = threadIdx.x;
    const int g0 = blockIdx.x * 8;
    for (int idx = t; idx < 8 * GD; idx += 256) {
        int ge = idx / GD, i = idx - ge * GD;
        gr[ge][i] = Grep[(g0 + ge) * GD + i];
    }
    __syncthreads();
    const int ge = t >> 5, kk = t & 31;
    float a = bg1[kk];
    for (int i = 0; i < GD; ++i) a += gr[ge][i] * Wg1[i * KD + kk];
    hq[ge][kk] = gelu_exact(a);
    __syncthreads();
    float b = bg2[kk];
#pragma unroll
    for (int j = 0; j < KD; ++j) b += hq[ge][j] * Wg2[j * KD + kk];
    float qv = b * 0.17677669529663687f; // fold 1/sqrt(d_k)
    const int g = g0 + ge;
    __hip_bfloat16 hi = __float2bfloat16(qv);
    float hif = __bfloat162float(hi);
    int idx = ((g >> 4) * 64 + (g & 15) + 16 * (kk >> 3)) * 8 + (kk & 7);
    qAhi[idx] = *reinterpret_cast<ushort*>(&hi);
    qAlo[idx] = bf16bits(qv - hif);
    float sq = qv * qv;
#pragma unroll
    for (int off = 16; off > 0; off >>= 1) sq += __shfl_xor(sq, off, 32);
    if (kk == 0) {
        float km2 = __uint_as_float(*kmax2u);
        // static softmax shift: upper bound on max_c(q.k_c + gumbel); exp(l-M) <= 1
        Mg[g] = sqrtf(sq * km2) + 25.0f;
    }
}

// ---------------- Kernel 3: genZB — gen_Z bf16, PV B-fragment order (validated)
__global__ void vprep_kernel(const float* __restrict__ genZ, ushort* __restrict__ genZB) {
    int o = blockIdx.x * 256 + threadIdx.x; // 1,048,576 total
    int j = o & 7;
    int l = (o >> 3) & 63;
    int db = (o >> 9) & 7;
    int cb = o >> 12;
    int c = cb * 32 + ((l >> 4) & 3) * 8 + j;
    int d = db * 16 + (l & 15);
    float v = (d < GD) ? genZ[d * NCELL + c] : 0.0f;
    genZB[o] = bf16bits(v);
}

// ---------------- Kernel 4: fused partial. Block = (gene-block gb, cell-quarter qq).
// 512 thr = 8 waves; chunks of 256 cells; wave w scores c-tiles {2w,2w+1} of the chunk,
// owns PV d-tile [16w,16w+16). Writes f32 partial acc + partial L (no normalize).
__launch_bounds__(512)
__global__ void fused_kernel(const float* __restrict__ gumbel,
                             const ushort* __restrict__ khiB, const ushort* __restrict__ kloB,
                             const ushort* __restrict__ qAhi, const ushort* __restrict__ qAlo,
                             const float* __restrict__ Mg,
                             const ushort* __restrict__ genZB,
                             float* __restrict__ part, float* __restrict__ Lpart,
                             int cells_pb) {
    __shared__ __align__(16) ushort p_lds[2 * 8192];  // 32 KB ping-pong, swizzled A-frag order
    __shared__ float M_lds[16];
    __shared__ float Lred[8][16];

    const int t = threadIdx.x, lane = t & 63, w = t >> 6;
    const int gb = blockIdx.x % NGB;
    const int qq = blockIdx.x / NGB;
    const int g0 = gb * 16;
    const int c_base = qq * cells_pb;
    const int nchunks = cells_pb >> 8;

    if (t < 16) M_lds[t] = Mg[g0 + t];
    short8 qhi = *reinterpret_cast<const short8*>(qAhi + (size_t)gb * 512 + lane * 8);
    short8 qlo = *reinterpret_cast<const short8*>(qAlo + (size_t)gb * 512 + lane * 8);
    __syncthreads();
    float Mvec[4];
#pragma unroll
    for (int r = 0; r < 4; ++r) Mvec[r] = M_lds[4 * (lane >> 4) + r];

    float L[4] = {0.f, 0.f, 0.f, 0.f};
    f32x4 accE = {0.f, 0.f, 0.f, 0.f}, accO = {0.f, 0.f, 0.f, 0.f};
    const float* grow = gumbel + (size_t)(g0 + 4 * (lane >> 4)) * NCELL + (lane & 15);
    const int wrbase = w * 1024 + ((lane & 15) >> 3) * 256 + (lane & 7) * 2;
    const short8* bfp = reinterpret_cast<const short8*>(genZB);
    char* pb = reinterpret_cast<char*>(p_lds);

    int pp = 0;
    for (int chunk = 0; chunk < nchunks; ++chunk) {
        const int ct0 = (c_base >> 4) + chunk * 16 + 2 * w;   // global c-tile index
        short8 kh0 = *reinterpret_cast<const short8*>(khiB + ct0 * 512 + lane * 8);
        short8 kl0 = *reinterpret_cast<const short8*>(kloB + ct0 * 512 + lane * 8);
        short8 kh1 = *reinterpret_cast<const short8*>(khiB + (ct0 + 1) * 512 + lane * 8);
        short8 kl1 = *reinterpret_cast<const short8*>(kloB + (ct0 + 1) * 512 + lane * 8);
        float gu0[4], gu1[4];
#pragma unroll
        for (int r = 0; r < 4; ++r) {
            gu0[r] = grow[(size_t)r * NCELL + ct0 * 16];
            gu1[r] = grow[(size_t)r * NCELL + (ct0 + 1) * 16];
        }
        // scores: split into 2 parallel chains (depth 2) then add
        f32x4 z4 = {0.f, 0.f, 0.f, 0.f};
        f32x4 s0a = __builtin_amdgcn_mfma_f32_16x16x32_bf16(qhi, kh0, z4, 0, 0, 0);
        f32x4 s0b = __builtin_amdgcn_mfma_f32_16x16x32_bf16(qhi, kl0, z4, 0, 0, 0);
        s0b = __builtin_amdgcn_mfma_f32_16x16x32_bf16(qlo, kh0, s0b, 0, 0, 0);
        f32x4 s1a = __builtin_amdgcn_mfma_f32_16x16x32_bf16(qhi, kh1, z4, 0, 0, 0);
        f32x4 s1b = __builtin_amdgcn_mfma_f32_16x16x32_bf16(qhi, kl1, z4, 0, 0, 0);
        s1b = __builtin_amdgcn_mfma_f32_16x16x32_bf16(qlo, kh1, s1b, 0, 0, 0);
        const int base = pp * 16384 + wrbase + 64 * (lane >> 4);
#pragma unroll
        for (int r = 0; r < 4; ++r) {
            float p0 = __expf(s0a[r] + s0b[r] + gu0[r] - Mvec[r]);
            float p1 = __expf(s1a[r] + s1b[r] + gu1[r] - Mvec[r]);
            L[r] += p0 + p1;
            int b0 = base + 16 * r;           // e = 0
            int b1 = b0 + 512;                // e = 1
            b0 ^= ((b0 >> 8) & 7) << 4;
            b1 ^= ((b1 >> 8) & 7) << 4;
            *reinterpret_cast<ushort*>(pb + b0) = bf16bits(p0);
            *reinterpret_cast<ushort*>(pb + b1) = bf16bits(p1);
        }
        __syncthreads();
        // PV over this chunk: 8 k-blocks of 32 cells, dual accumulators
        if (w < 7) {   // d-tile 7 is all-pad (d >= 112)
            const int gkb0 = (c_base >> 5) + chunk * 8;
#pragma unroll
            for (int kb = 0; kb < 8; ++kb) {
                int rbyte = pp * 16384 + kb * 1024 + lane * 16;
                rbyte ^= ((rbyte >> 8) & 7) << 4;
                short8 a = *reinterpret_cast<const short8*>(pb + rbyte);
                short8 b = bfp[((gkb0 + kb) * 8 + w) * 64 + lane];
                if (kb & 1) accO = __builtin_amdgcn_mfma_f32_16x16x32_bf16(a, b, accO, 0, 0, 0);
                else        accE = __builtin_amdgcn_mfma_f32_16x16x32_bf16(a, b, accE, 0, 0, 0);
            }
        }
        pp ^= 1;
    }
    // ---- partial L reduction: lanes sharing (lane>>4) hold disjoint-cell partials
#pragma unroll
    for (int r = 0; r < 4; ++r) {
        float v = L[r];
        v += __shfl_xor(v, 1, 64);
        v += __shfl_xor(v, 2, 64);
        v += __shfl_xor(v, 4, 64);
        v += __shfl_xor(v, 8, 64);
        L[r] = v;
    }
    if ((lane & 15) == 0) {
#pragma unroll
        for (int r = 0; r < 4; ++r) Lred[w][4 * (lane >> 4) + r] = L[r];
    }
    __syncthreads();
    if (t < 16) {
        float s = 0.f;
#pragma unroll
        for (int ww = 0; ww < 8; ++ww) s += Lred[ww][t];
        Lpart[(size_t)blockIdx.x * 16 + t] = s;
    }
    f32x4 acc = accE + accO;
    const int d = 16 * w + (lane & 15);
    if (d < GD) {
        const int gl0 = (lane >> 4) * 4;  // C/D: col=lane&15 (d), row=(lane>>4)*4+r (gene)
        *reinterpret_cast<f32x4*>(part + ((size_t)blockIdx.x * GD + d) * 16 + gl0) = acc;
    }
}

// ---------------- Kernel 5: combine partials + normalize
__global__ void combine_kernel(const float* __restrict__ part, const float* __restrict__ Lpart,
                               int nq, float* __restrict__ out) {
    const int gb = blockIdx.x;
    const int t = threadIdx.x;
    __shared__ float Linv[16];
    if (t < 16) {
        float s = 0.f;
        for (int q = 0; q < nq; ++q) s += Lpart[(size_t)(q * NGB + gb) * 16 + t];
        Linv[t] = 1.0f / s;
    }
    __syncthreads();
    for (int idx = t; idx < GD * 16; idx += 256) {
        const int d = idx >> 4, g = idx & 15;
        float s = 0.f;
        for (int q = 0; q < nq; ++q)
            s += part[((size_t)(q * NGB + gb) * GD + d) * 16 + g];
        out[(size_t)d * NGENE + gb * 16 + g] = s * Linv[g];
    }
}

extern "C" void kernel_launch(void* const* d_in, const int* in_sizes, int n_in,
                              void* d_out, int out_size, void* d_ws, size_t ws_size,
                              hipStream_t stream) {
    const float* rawZ  = (const float*)d_in[0];
    const float* genZ  = (const float*)d_in[1];
    const float* Grep  = (const float*)d_in[2];
    const float* gumb  = (const float*)d_in[3];
    const float* Wz1   = (const float*)d_in[4];
    const float* bz1   = (const float*)d_in[5];
    const float* Wz2   = (const float*)d_in[6];
    const float* bz2   = (const float*)d_in[7];
    const float* Wg1   = (const float*)d_in[8];
    const float* bg1   = (const float*)d_in[9];
    const float* Wg2   = (const float*)d_in[10];
    const float* bg2   = (const float*)d_in[11];
    float* out = (float*)d_out;

    // ws: khiB 512K | kloB 512K | qAhi 640K | qAlo 640K | genZB 2M | Mg 40K | kmax 256B | part | Lpart
    char* ws = (char*)d_ws;
    ushort*   khiB = (ushort*)ws;
    ushort*   kloB = (ushort*)(ws + 524288);
    ushort*   qAhi = (ushort*)(ws + 1048576);
    ushort*   qAlo = (ushort*)(ws + 1048576 + 655360);
    ushort*   genZB = (ushort*)(ws + 1048576 + 2 * 655360);
    float*    MgA  = (float*)(ws + 1048576 + 2 * 655360 + 2097152);
    unsigned* kmax = (unsigned*)(ws + 1048576 + 2 * 655360 + 2097152 + 40960);
    const size_t part_off = 1048576 + 2 * 655360 + 2097152 + 40960 + 256;

    // pick cell-split factor that fits the workspace (deterministic given fixed ws_size)
    int nq = 4;
    while (nq > 1 && part_off + (size_t)nq * NGB * (GD * 16 + 16) * 4 > ws_size) nq >>= 1;
    float* partA = (float*)(ws + part_off);
    float* LpartA = partA + (size_t)nq * NGB * GD * 16;

    hipMemsetAsync(kmax, 0, 4, stream);
    hipLaunchKernelGGL(key_kernel,   dim3(NCELL / 8), dim3(256), 0, stream,
                       rawZ, Wz1, bz1, Wz2, bz2, khiB, kloB, kmax);
    hipLaunchKernelGGL(query_kernel, dim3(NGENE / 8), dim3(256), 0, stream,
                       Grep, Wg1, bg1, Wg2, bg2, kmax, qAhi, qAlo, MgA);
    hipLaunchKernelGGL(vprep_kernel, dim3((256 * 8 * 64 * 8) / 256), dim3(256), 0, stream,
                       genZ, genZB);
    hipLaunchKernelGGL(fused_kernel, dim3(NGB * nq), dim3(512), 0, stream,
                       gumb, khiB, kloB, qAhi, qAlo, MgA, genZB, partA, LpartA, NCELL / nq);
    hipLaunchKernelGGL(combine_kernel, dim3(NGB), dim3(256), 0, stream,
                       partA, LpartA, nq, out);
}

// Round 5
// 249.323 us; speedup vs baseline: 1.0878x; 1.0878x over previous
//
#include <hip/hip_runtime.h>
#include <hip/hip_bf16.h>

typedef __attribute__((ext_vector_type(8))) short short8;
typedef __attribute__((ext_vector_type(4))) float f32x4;
typedef __attribute__((ext_vector_type(2))) float f32x2;
typedef __attribute__((ext_vector_type(4))) unsigned uint4v;
typedef __attribute__((ext_vector_type(2))) unsigned uint2v;

#define NCELL 8192
#define NGENE 10000
#define KD 32
#define ZD 100
#define HD 256
#define GD 100   // z_dim of output (gen_Z rows)
#define NGB 625  // gene blocks of 16

__device__ __forceinline__ float gelu_exact(float x) {
    return 0.5f * x * (1.0f + erff(x * 0.70710678118654752f));
}
__device__ __forceinline__ ushort bf16bits(float x) {
    __hip_bfloat16 h = __float2bfloat16(x);
    return *reinterpret_cast<ushort*>(&h);
}

// ---------------- Kernel 1: keys -> bf16 hi/lo A-fragments for S^T.
// A-frag: lane row = SLOT s (permuted cell-within-tile), k = 8*(lane>>4)+j.
// Slot perm (makes cvt_pk+permlane output have k == linear cell): s = {c1,c3,c2,c0} -> bits {3,2,1,0}
__global__ void key_kernel(const float* __restrict__ rawZ,
                           const float* __restrict__ Wz1, const float* __restrict__ bz1,
                           const float* __restrict__ Wz2, const float* __restrict__ bz2,
                           ushort* __restrict__ khiA, ushort* __restrict__ kloA,
                           unsigned* __restrict__ kmax2u) {
    __shared__ float z[8][ZD];
    __shared__ float h[8][HD];
    const int t = threadIdx.x;
    const int c0 = blockIdx.x * 8;
    for (int idx = t; idx < 8 * ZD; idx += 256) {
        int cell = idx / ZD, i = idx - cell * ZD;
        z[cell][i] = rawZ[i * NCELL + c0 + cell];
    }
    __syncthreads();
    float a[8];
#pragma unroll
    for (int cl = 0; cl < 8; ++cl) a[cl] = bz1[t];
    for (int i = 0; i < ZD; ++i) {
        float wv = Wz1[i * HD + t];
#pragma unroll
        for (int cl = 0; cl < 8; ++cl) a[cl] += z[cl][i] * wv;
    }
#pragma unroll
    for (int cl = 0; cl < 8; ++cl) h[cl][t] = gelu_exact(a[cl]);
    __syncthreads();
    const int cell = t >> 5, kk = t & 31;
    float b = bz2[kk];
    for (int j = 0; j < HD; ++j) b += h[cell][j] * Wz2[j * KD + kk];
    const int c = c0 + cell;
    const int c16 = c & 15;
    const int s = (c16 & 1) | (((c16 >> 2) & 1) << 1) | (((c16 >> 3) & 1) << 2) | (((c16 >> 1) & 1) << 3);
    __hip_bfloat16 hi = __float2bfloat16(b);
    float hif = __bfloat162float(hi);
    int idx = ((c >> 4) * 64 + s + 16 * (kk >> 3)) * 8 + (kk & 7);
    khiA[idx] = *reinterpret_cast<ushort*>(&hi);
    kloA[idx] = bf16bits(b - hif);
    float sq = b * b;
#pragma unroll
    for (int off = 16; off > 0; off >>= 1) sq += __shfl_xor(sq, off, 32);
    if (kk == 0) atomicMax(kmax2u, __float_as_uint(sq));
}

// ---------------- Kernel 2: q -> bf16 hi/lo B-fragments (col=g&15, k=8*(l>>4)+j), Mg bound
__global__ void query_kernel(const float* __restrict__ Grep,
                             const float* __restrict__ Wg1, const float* __restrict__ bg1,
                             const float* __restrict__ Wg2, const float* __restrict__ bg2,
                             const unsigned* __restrict__ kmax2u,
                             ushort* __restrict__ qBhi, ushort* __restrict__ qBlo,
                             float* __restrict__ Mg) {
    __shared__ float gr[8][GD];
    __shared__ float hq[8][KD];
    const int t = threadIdx.x;
    const int g0 = blockIdx.x * 8;
    for (int idx = t; idx < 8 * GD; idx += 256) {
        int ge = idx / GD, i = idx - ge * GD;
        gr[ge][i] = Grep[(g0 + ge) * GD + i];
    }
    __syncthreads();
    const int ge = t >> 5, kk = t & 31;
    float a = bg1[kk];
    for (int i = 0; i < GD; ++i) a += gr[ge][i] * Wg1[i * KD + kk];
    hq[ge][kk] = gelu_exact(a);
    __syncthreads();
    float b = bg2[kk];
#pragma unroll
    for (int j = 0; j < KD; ++j) b += hq[ge][j] * Wg2[j * KD + kk];
    float qv = b * 0.17677669529663687f; // fold 1/sqrt(d_k)
    const int g = g0 + ge;
    __hip_bfloat16 hi = __float2bfloat16(qv);
    float hif = __bfloat162float(hi);
    int idx = ((g >> 4) * 64 + (g & 15) + 16 * (kk >> 3)) * 8 + (kk & 7);
    qBhi[idx] = *reinterpret_cast<ushort*>(&hi);
    qBlo[idx] = bf16bits(qv - hif);
    float sq = qv * qv;
#pragma unroll
    for (int off = 16; off > 0; off >>= 1) sq += __shfl_xor(sq, off, 32);
    if (kk == 0) {
        float km2 = __uint_as_float(*kmax2u);
        Mg[g] = sqrtf(sq * km2) + 25.0f;   // static softmax shift; exp(l-M) <= 1 always
    }
}

// ---------------- Kernel 3: genZB — gen_Z bf16, PV B-fragment order, k = linear cell (validated)
__global__ void vprep_kernel(const float* __restrict__ genZ, ushort* __restrict__ genZB) {
    int o = blockIdx.x * 256 + threadIdx.x; // 1,048,576 total
    int j = o & 7;
    int l = (o >> 3) & 63;
    int db = (o >> 9) & 7;
    int cb = o >> 12;
    int c = cb * 32 + ((l >> 4) & 3) * 8 + j;
    int d = db * 16 + (l & 15);
    float v = (d < GD) ? genZ[d * NCELL + c] : 0.0f;
    genZB[o] = bf16bits(v);
}

// ---------------- Kernel 4: barrier-free fused attention partial.
// One wave = 16 genes x (8192/Q) cells, fully independent. S^T via MFMA (A=K,B=Q),
// static-max exp in C/D layout, cvt_pk+permlane32_swap -> PV A-frag in-register,
// 7 PV MFMAs/step. Gumbel transposed through wave-private 2KB LDS dbuf (XOR-swizzled).
__launch_bounds__(256, 4)
__global__ void fused_kernel(const float* __restrict__ gumbel,
                             const ushort* __restrict__ khiA, const ushort* __restrict__ kloA,
                             const ushort* __restrict__ qBhi, const ushort* __restrict__ qBlo,
                             const float* __restrict__ Mg,
                             const ushort* __restrict__ genZB,
                             float* __restrict__ part, float* __restrict__ Lpart,
                             int Q, int cells_pw) {
    __shared__ __align__(16) float glds[4][2][512];   // 16 KB: 4 waves x dbuf x 2KB
    const int t = threadIdx.x, lane = t & 63, w = t >> 6;
    const int wv = blockIdx.x * 4 + w;
    if (wv >= NGB * Q) return;
    const int gb = wv % NGB;
    const int q  = wv / NGB;
    const int g0 = gb * 16;
    const int cbase = q * cells_pw;
    const int nsteps = cells_pw >> 5;

    const float negM = -Mg[g0 + (lane & 15)];
    short8 qhi = *reinterpret_cast<const short8*>(qBhi + (size_t)gb * 512 + lane * 8);
    short8 qlo = *reinterpret_cast<const short8*>(qBlo + (size_t)gb * 512 + lane * 8);

    // gumbel global: lane loads row g0+(lane>>2), cols cbase+(lane&3)*8 .. +7 (2x f32x4)
    const float* gptr = gumbel + (size_t)(g0 + (lane >> 2)) * NCELL + cbase + (lane & 3) * 8;
    // LDS tile [16 genes][32 cells] f32, float-index = g*32 + (cell ^ ((g&7)<<2))
    float* wlds = &glds[w][0][0];
    const int gw = lane >> 2, ew = gw & 7;
    const int wr0 = gw * 32 + (((lane & 3) * 8)     ^ (ew << 2));
    const int wr1 = gw * 32 + (((lane & 3) * 8 + 4) ^ (ew << 2));
    const int gr = lane & 15, er = gr & 7, b = lane >> 4;
    const int clo = 2 * (b >> 1) + 8 * (b & 1);      // inverse slot perm, r-offsets {0,1,4,5}
    const int rd0 = gr * 32 + ((clo)      ^ (er << 2));
    const int rd1 = gr * 32 + ((clo + 4)  ^ (er << 2));
    const int rd2 = gr * 32 + ((clo + 16) ^ (er << 2));
    const int rd3 = gr * 32 + ((clo + 20) ^ (er << 2));

    // prologue: stage step-0 gumbel into buf0
    {
        f32x4 a0 = *reinterpret_cast<const f32x4*>(gptr);
        f32x4 a1 = *reinterpret_cast<const f32x4*>(gptr + 4);
        *reinterpret_cast<f32x4*>(wlds + wr0) = a0;
        *reinterpret_cast<f32x4*>(wlds + wr1) = a1;
    }

    f32x4 acc[7];
#pragma unroll
    for (int i = 0; i < 7; ++i) acc[i] = f32x4{0.f, 0.f, 0.f, 0.f};
    float L = 0.f;
    int cur = 0;
    const ushort* kp  = khiA + (size_t)(cbase >> 4) * 512 + lane * 8;
    const ushort* klp = kloA + (size_t)(cbase >> 4) * 512 + lane * 8;
    const short8* vb  = reinterpret_cast<const short8*>(genZB) + (size_t)(cbase >> 5) * 512 + lane;
    const f32x4 z4 = {0.f, 0.f, 0.f, 0.f};

    for (int i = 0; i < nsteps; ++i) {
        // k-fragments for the 2 c-tiles of this 32-cell step
        short8 kh0 = *reinterpret_cast<const short8*>(kp);
        short8 kh1 = *reinterpret_cast<const short8*>(kp + 512);
        short8 kl0 = *reinterpret_cast<const short8*>(klp);
        short8 kl1 = *reinterpret_cast<const short8*>(klp + 512);
        kp += 1024; klp += 1024;
        // next-step gumbel (global, coalesced); clamp on last iter
        const int inext = (i + 1 < nsteps) ? (i + 1) : i;
        const float* gp2 = gptr + (size_t)inext * 32;
        f32x4 gnA = *reinterpret_cast<const f32x4*>(gp2);
        f32x4 gnB = *reinterpret_cast<const f32x4*>(gp2 + 4);
        // current gumbel from LDS (slot-permuted pairs)
        const float* rbuf = wlds + cur * 512;
        f32x2 u0 = *reinterpret_cast<const f32x2*>(rbuf + rd0);
        f32x2 u1 = *reinterpret_cast<const f32x2*>(rbuf + rd1);
        f32x2 u2 = *reinterpret_cast<const f32x2*>(rbuf + rd2);
        f32x2 u3 = *reinterpret_cast<const f32x2*>(rbuf + rd3);
        // S^T = K x Q, 3-term bf16 split (exact to ~2^-17)
        f32x4 s0 = __builtin_amdgcn_mfma_f32_16x16x32_bf16(kh0, qhi, z4, 0, 0, 0);
        s0 = __builtin_amdgcn_mfma_f32_16x16x32_bf16(kl0, qhi, s0, 0, 0, 0);
        s0 = __builtin_amdgcn_mfma_f32_16x16x32_bf16(kh0, qlo, s0, 0, 0, 0);
        f32x4 s1 = __builtin_amdgcn_mfma_f32_16x16x32_bf16(kh1, qhi, z4, 0, 0, 0);
        s1 = __builtin_amdgcn_mfma_f32_16x16x32_bf16(kl1, qhi, s1, 0, 0, 0);
        s1 = __builtin_amdgcn_mfma_f32_16x16x32_bf16(kh1, qlo, s1, 0, 0, 0);
        // V fragments (7 d-tiles)
        short8 v0 = vb[0],   v1 = vb[64],  v2 = vb[128], v3 = vb[192];
        short8 v4 = vb[256], v5 = vb[320], v6 = vb[384];
        vb += 512;
        // exp(S + gumbel - M); P <= 1 guaranteed
        float p0 = __expf(s0.x + u0.x + negM);
        float p1 = __expf(s0.y + u0.y + negM);
        float p2 = __expf(s0.z + u1.x + negM);
        float p3 = __expf(s0.w + u1.y + negM);
        float p4 = __expf(s1.x + u2.x + negM);
        float p5 = __expf(s1.y + u2.y + negM);
        float p6 = __expf(s1.z + u3.x + negM);
        float p7 = __expf(s1.w + u3.y + negM);
        L += ((p0 + p1) + (p2 + p3)) + ((p4 + p5) + (p6 + p7));
        // pack to bf16 pairs, then swap halves -> PA fragment with k == linear cell
        unsigned w00, w01, w10, w11;
        asm("v_cvt_pk_bf16_f32 %0, %1, %2" : "=v"(w00) : "v"(p0), "v"(p1));
        asm("v_cvt_pk_bf16_f32 %0, %1, %2" : "=v"(w01) : "v"(p2), "v"(p3));
        asm("v_cvt_pk_bf16_f32 %0, %1, %2" : "=v"(w10) : "v"(p4), "v"(p5));
        asm("v_cvt_pk_bf16_f32 %0, %1, %2" : "=v"(w11) : "v"(p6), "v"(p7));
        uint2v rA = __builtin_amdgcn_permlane32_swap(w00, w10, false, false);
        uint2v rB = __builtin_amdgcn_permlane32_swap(w01, w11, false, false);
        uint4v pau = {rA.x, rA.y, rB.x, rB.y};
        short8 pa = *reinterpret_cast<short8*>(&pau);
        // PV: 7 independent MFMAs
        acc[0] = __builtin_amdgcn_mfma_f32_16x16x32_bf16(pa, v0, acc[0], 0, 0, 0);
        acc[1] = __builtin_amdgcn_mfma_f32_16x16x32_bf16(pa, v1, acc[1], 0, 0, 0);
        acc[2] = __builtin_amdgcn_mfma_f32_16x16x32_bf16(pa, v2, acc[2], 0, 0, 0);
        acc[3] = __builtin_amdgcn_mfma_f32_16x16x32_bf16(pa, v3, acc[3], 0, 0, 0);
        acc[4] = __builtin_amdgcn_mfma_f32_16x16x32_bf16(pa, v4, acc[4], 0, 0, 0);
        acc[5] = __builtin_amdgcn_mfma_f32_16x16x32_bf16(pa, v5, acc[5], 0, 0, 0);
        acc[6] = __builtin_amdgcn_mfma_f32_16x16x32_bf16(pa, v6, acc[6], 0, 0, 0);
        // stage next gumbel into the other buffer (wave-private; waitcnt-ordered, no barrier)
        float* wbuf = wlds + (cur ^ 1) * 512;
        *reinterpret_cast<f32x4*>(wbuf + wr0) = gnA;
        *reinterpret_cast<f32x4*>(wbuf + wr1) = gnB;
        cur ^= 1;
    }
    // L: lanes with same (lane&15) hold disjoint partials of the same gene
    L += __shfl_xor(L, 16, 64);
    L += __shfl_xor(L, 32, 64);
    if (lane < 16) Lpart[(size_t)wv * 16 + lane] = L;
    float* pp = part + (size_t)wv * 7 * 256;
#pragma unroll
    for (int db = 0; db < 7; ++db)
        *reinterpret_cast<f32x4*>(pp + db * 256 + lane * 4) = acc[db];
}

// ---------------- Kernel 5: combine partials + normalize
__global__ void combine_kernel(const float* __restrict__ part, const float* __restrict__ Lpart,
                               int Q, float* __restrict__ out) {
    const int gb = blockIdx.x;
    const int t = threadIdx.x;
    __shared__ float Linv[16];
    if (t < 16) {
        float s = 0.f;
        for (int qq = 0; qq < Q; ++qq) s += Lpart[(size_t)(qq * NGB + gb) * 16 + t];
        Linv[t] = 1.0f / s;
    }
    __syncthreads();
    if (t < 448) {
        const int db = t >> 6, lane = t & 63;
        const int d = db * 16 + (lane & 15);
        f32x4 ssum = {0.f, 0.f, 0.f, 0.f};
        for (int qq = 0; qq < Q; ++qq)
            ssum += *reinterpret_cast<const f32x4*>(
                part + (((size_t)(qq * NGB + gb) * 7 + db) * 64 + lane) * 4);
        if (d < GD) {
            const int gl0 = 4 * (lane >> 4);   // C/D: col=lane&15 (d), row=4*(lane>>4)+r (gene)
            f32x4 li = {Linv[gl0], Linv[gl0 + 1], Linv[gl0 + 2], Linv[gl0 + 3]};
            f32x4 o = ssum * li;
            *reinterpret_cast<f32x4*>(out + (size_t)d * NGENE + gb * 16 + gl0) = o;
        }
    }
}

extern "C" void kernel_launch(void* const* d_in, const int* in_sizes, int n_in,
                              void* d_out, int out_size, void* d_ws, size_t ws_size,
                              hipStream_t stream) {
    const float* rawZ  = (const float*)d_in[0];
    const float* genZ  = (const float*)d_in[1];
    const float* Grep  = (const float*)d_in[2];
    const float* gumb  = (const float*)d_in[3];
    const float* Wz1   = (const float*)d_in[4];
    const float* bz1   = (const float*)d_in[5];
    const float* Wz2   = (const float*)d_in[6];
    const float* bz2   = (const float*)d_in[7];
    const float* Wg1   = (const float*)d_in[8];
    const float* bg1   = (const float*)d_in[9];
    const float* Wg2   = (const float*)d_in[10];
    const float* bg2   = (const float*)d_in[11];
    float* out = (float*)d_out;

    char* ws = (char*)d_ws;
    ushort*   khiA = (ushort*)ws;
    ushort*   kloA = (ushort*)(ws + 524288);
    ushort*   qBhi = (ushort*)(ws + 1048576);
    ushort*   qBlo = (ushort*)(ws + 1048576 + 655360);
    ushort*   genZB = (ushort*)(ws + 1048576 + 2 * 655360);
    float*    MgA  = (float*)(ws + 1048576 + 2 * 655360 + 2097152);
    unsigned* kmax = (unsigned*)(ws + 1048576 + 2 * 655360 + 2097152 + 40960);
    const size_t base_off = 1048576 + 2 * 655360 + 2097152 + 40960 + 256;

    // cell-split factor: waves = 625*Q; fall back if workspace too small
    int Q = 8;
    while (Q > 1 && base_off + (size_t)Q * NGB * (7 * 256 + 16) * 4 > ws_size) Q >>= 1;
    float* partA  = (float*)(ws + base_off);
    float* LpartA = partA + (size_t)Q * NGB * 7 * 256;

    hipMemsetAsync(kmax, 0, 4, stream);
    hipLaunchKernelGGL(key_kernel,   dim3(NCELL / 8), dim3(256), 0, stream,
                       rawZ, Wz1, bz1, Wz2, bz2, khiA, kloA, kmax);
    hipLaunchKernelGGL(query_kernel, dim3(NGENE / 8), dim3(256), 0, stream,
                       Grep, Wg1, bg1, Wg2, bg2, kmax, qBhi, qBlo, MgA);
    hipLaunchKernelGGL(vprep_kernel, dim3((256 * 8 * 64 * 8) / 256), dim3(256), 0, stream,
                       genZ, genZB);
    hipLaunchKernelGGL(fused_kernel, dim3((NGB * Q + 3) / 4), dim3(256), 0, stream,
                       gumb, khiA, kloA, qBhi, qBlo, MgA, genZB, partA, LpartA,
                       Q, NCELL / Q);
    hipLaunchKernelGGL(combine_kernel, dim3(NGB), dim3(512), 0, stream,
                       partA, LpartA, Q, out);
}